// Round 2
// baseline (476.171 us; speedup 1.0000x reference)
//
#include <hip/hip_runtime.h>
#include <cstdint>
#include <cstddef>

// ---------------------------------------------------------------------------
// EncoderBlock: pre-norm transformer block, **f32 I/O**, bf16 MFMA internals.
// Pipeline:
//   T(weights f32->bf16) -> LN1(f32->bf16) -> GEMM(QKV fused) -> T(V) ->
//   flash-attn -> GEMM(Wo,+b,+x[f32]) -> x1(f32) -> LN2 -> GEMM(W1,+b,relu)
//   -> GEMM(W2,+b,+x1) -> d_out (f32)
// GEMMs: m97 structure, 128x128 tile, BK=32, global_load_lds(16B),
// mfma_f32_16x16x32_bf16, B supplied transposed [N,K] in bf16.
// ---------------------------------------------------------------------------

typedef __attribute__((ext_vector_type(8))) __bf16 bf16x8;
typedef __attribute__((ext_vector_type(4))) float f32x4;

__device__ __forceinline__ void async16(const void* g, void* l) {
  __builtin_amdgcn_global_load_lds(
      (__attribute__((address_space(1))) void*)g,
      (__attribute__((address_space(3))) void*)l, 16, 0, 0);
}

__device__ __forceinline__ f32x4 mfma16(bf16x8 a, bf16x8 b, f32x4 c) {
  return __builtin_amdgcn_mfma_f32_16x16x32_bf16(a, b, c, 0, 0, 0);
}

// ---------------------------------------------------------------------------
// f32 -> bf16 converting transpose: out[C][R] = (bf16)in[R][C].
// Grid (C/64, R/64), 256 thr.
// ---------------------------------------------------------------------------
__global__ __launch_bounds__(256) void transpose_f2b(
    const float* __restrict__ in, __bf16* __restrict__ out, int ld_in,
    int ld_out) {
  __shared__ __bf16 tile[64][65];
  const int c0 = blockIdx.x * 64, r0 = blockIdx.y * 64;
  const int tx = threadIdx.x & 63, ty = threadIdx.x >> 6;
#pragma unroll
  for (int i = 0; i < 16; i++) {
    int r = ty + i * 4;
    tile[r][tx] = (__bf16)in[(size_t)(r0 + r) * ld_in + c0 + tx];
  }
  __syncthreads();
#pragma unroll
  for (int i = 0; i < 16; i++) {
    int r = ty + i * 4;
    out[(size_t)(c0 + r) * ld_out + r0 + tx] = tile[tx][r];
  }
}

// ---------------------------------------------------------------------------
// bf16 transpose (for V^T from QKV). out[C][R] = in[R][C].
// ---------------------------------------------------------------------------
__global__ __launch_bounds__(256) void transpose_bf16(
    const unsigned short* __restrict__ in, unsigned short* __restrict__ out,
    int ld_in, int ld_out) {
  __shared__ unsigned short tile[64][65];
  const int c0 = blockIdx.x * 64, r0 = blockIdx.y * 64;
  const int tx = threadIdx.x & 63, ty = threadIdx.x >> 6;
#pragma unroll
  for (int i = 0; i < 16; i++) {
    int r = ty + i * 4;
    tile[r][tx] = in[(size_t)(r0 + r) * ld_in + c0 + tx];
  }
  __syncthreads();
#pragma unroll
  for (int i = 0; i < 16; i++) {
    int r = ty + i * 4;
    out[(size_t)(c0 + r) * ld_out + r0 + tx] = tile[tx][r];
  }
}

// ---------------------------------------------------------------------------
// LayerNorm over 1024 dims. f32 input, f32 gamma/beta, bf16 output.
// One wave per token, 4 tokens/block, grid=1024.
// ---------------------------------------------------------------------------
__global__ __launch_bounds__(256) void ln_kernel(
    const float* __restrict__ xin, const float* __restrict__ g,
    const float* __restrict__ bt, __bf16* __restrict__ out) {
  const int tok = blockIdx.x * 4 + (threadIdx.x >> 6);
  const int lane = threadIdx.x & 63;
  const int base0 = lane * 8, base1 = 512 + lane * 8;
  const float* xr = xin + (size_t)tok * 1024;
  float v[16];
  float4 a0 = *(const float4*)(xr + base0);
  float4 a1 = *(const float4*)(xr + base0 + 4);
  float4 a2 = *(const float4*)(xr + base1);
  float4 a3 = *(const float4*)(xr + base1 + 4);
  v[0] = a0.x; v[1] = a0.y; v[2] = a0.z; v[3] = a0.w;
  v[4] = a1.x; v[5] = a1.y; v[6] = a1.z; v[7] = a1.w;
  v[8] = a2.x; v[9] = a2.y; v[10] = a2.z; v[11] = a2.w;
  v[12] = a3.x; v[13] = a3.y; v[14] = a3.z; v[15] = a3.w;
  float s = 0.f, s2 = 0.f;
#pragma unroll
  for (int i = 0; i < 16; i++) { s += v[i]; s2 += v[i] * v[i]; }
#pragma unroll
  for (int m = 1; m < 64; m <<= 1) {
    s += __shfl_xor(s, m);
    s2 += __shfl_xor(s2, m);
  }
  const float mean = s * (1.f / 1024.f);
  const float var = s2 * (1.f / 1024.f) - mean * mean;
  const float rstd = rsqrtf(var + 1e-6f);
  float4 g0 = *(const float4*)(g + base0), g1 = *(const float4*)(g + base0 + 4);
  float4 g2 = *(const float4*)(g + base1), g3 = *(const float4*)(g + base1 + 4);
  float4 b0 = *(const float4*)(bt + base0), b1v = *(const float4*)(bt + base0 + 4);
  float4 b2v = *(const float4*)(bt + base1), b3 = *(const float4*)(bt + base1 + 4);
  float gg[16] = {g0.x, g0.y, g0.z, g0.w, g1.x, g1.y, g1.z, g1.w,
                  g2.x, g2.y, g2.z, g2.w, g3.x, g3.y, g3.z, g3.w};
  float bb[16] = {b0.x, b0.y, b0.z, b0.w, b1v.x, b1v.y, b1v.z, b1v.w,
                  b2v.x, b2v.y, b2v.z, b2v.w, b3.x, b3.y, b3.z, b3.w};
  bf16x8 o0, o1;
#pragma unroll
  for (int j = 0; j < 8; j++) {
    o0[j] = (__bf16)((v[j] - mean) * rstd * gg[j] + bb[j]);
    o1[j] = (__bf16)((v[8 + j] - mean) * rstd * gg[8 + j] + bb[8 + j]);
  }
  __bf16* op = out + (size_t)tok * 1024;
  *(bf16x8*)(op + base0) = o0;
  *(bf16x8*)(op + base1) = o1;
}

// ---------------------------------------------------------------------------
// GEMM C[M,N] = A[M,K](bf16) * BT[N,K](bf16)^T (+epilogue). 128x128 tile,
// BK=32, 256 threads = 2x2 waves of 64x64.
// EPI: 0 plain -> bf16
//      1 +bias(f32) +res(f32) -> f32
//      2 +bias(f32), relu -> bf16
//      3 +bias(f32) +res(f32) -> f32   (same as 1; kept for clarity)
// ---------------------------------------------------------------------------
template <int EPI>
__global__ __launch_bounds__(256) void gemm_bt(
    const __bf16* __restrict__ A, int lda, const __bf16* __restrict__ BT,
    int ldb, void* __restrict__ C, int ldc, int K,
    const float* __restrict__ bias, const float* __restrict__ res, int ldres) {
  const int t = threadIdx.x;
  const int m0 = blockIdx.y * 128, n0 = blockIdx.x * 128;
  __shared__ __align__(16) __bf16 As[128 * 32];  // [m][k]
  __shared__ __align__(16) __bf16 Bs[128 * 32];  // [n][k]
  const int lane = t & 63, w = t >> 6;
  const int quad = lane >> 4, l15 = lane & 15;
  const int wm = w >> 1, wn = w & 1;

  f32x4 acc[4][4] = {};

  const __bf16* ga = A + (size_t)(m0 + (t >> 2)) * lda + (t & 3) * 8;
  const __bf16* gb = BT + (size_t)(n0 + (t >> 2)) * ldb + (t & 3) * 8;
  __bf16* la = As + t * 8;
  __bf16* lb = Bs + t * 8;
  const size_t a64 = (size_t)64 * lda, b64 = (size_t)64 * ldb;

  for (int kk = 0; kk < K; kk += 32) {
    async16(ga, la);
    async16(ga + a64, la + 2048);
    async16(gb, lb);
    async16(gb + b64, lb + 2048);
    ga += 32;
    gb += 32;
    __syncthreads();  // vmcnt(0) drain before barrier -> LDS data visible
    bf16x8 af[4], bfr[4];
#pragma unroll
    for (int i = 0; i < 4; i++)
      af[i] = *(const bf16x8*)&As[(wm * 64 + i * 16 + l15) * 32 + quad * 8];
#pragma unroll
    for (int i = 0; i < 4; i++)
      bfr[i] = *(const bf16x8*)&Bs[(wn * 64 + i * 16 + l15) * 32 + quad * 8];
#pragma unroll
    for (int mi = 0; mi < 4; mi++)
#pragma unroll
      for (int ni = 0; ni < 4; ni++)
        acc[mi][ni] = mfma16(af[mi], bfr[ni], acc[mi][ni]);
    __syncthreads();
  }

  float biasv[4];
  if constexpr (EPI != 0) {
#pragma unroll
    for (int ni = 0; ni < 4; ni++)
      biasv[ni] = bias[n0 + wn * 64 + ni * 16 + l15];
  }
#pragma unroll
  for (int mi = 0; mi < 4; mi++)
#pragma unroll
    for (int ni = 0; ni < 4; ni++)
#pragma unroll
      for (int r = 0; r < 4; r++) {
        const int row = m0 + wm * 64 + mi * 16 + quad * 4 + r;
        const int col = n0 + wn * 64 + ni * 16 + l15;
        float v = acc[mi][ni][r];
        if constexpr (EPI == 0) {
          ((__bf16*)C)[(size_t)row * ldc + col] = (__bf16)v;
        } else if constexpr (EPI == 1 || EPI == 3) {
          v += biasv[ni] + res[(size_t)row * ldres + col];
          ((float*)C)[(size_t)row * ldc + col] = v;
        } else {  // EPI == 2
          v += biasv[ni];
          ((__bf16*)C)[(size_t)row * ldc + col] = (__bf16)fmaxf(v, 0.f);
        }
      }
}

// ---------------------------------------------------------------------------
// Flash attention (no mask). Block = (q-tile of 128) x (one b,h). 256 thr,
// wave w owns 32 q-rows. Q/K from QKV[tok][3072] (Q cols 0..1023, K 1024..2047),
// V via VT[1024][4096] (pre-transposed). log2(e)/8 folded into Q; softmax in
// exp2 domain. P goes C-layout -> LDS -> A-layout for the PV MFMA.
// ---------------------------------------------------------------------------
__global__ __launch_bounds__(256) void attn_kernel(
    const __bf16* __restrict__ QKV, const __bf16* __restrict__ VT,
    __bf16* __restrict__ ctx) {
  const int qt = blockIdx.x, bh = blockIdx.y;
  const int b = bh >> 4, h = bh & 15;
  const int t = threadIdx.x, w = t >> 6, lane = t & 63;
  const int quad = lane >> 4, l15 = lane & 15;
  const int tok0 = b * 2048, q0 = tok0 + qt * 128;

  __shared__ __align__(16) __bf16 Ks[128 * 64];     // [key][d]
  __shared__ __align__(16) __bf16 VTs[64 * 128];    // [d][key]
  __shared__ __align__(16) __bf16 Ps[4][32 * 128];  // per-wave [q][key]

  const float qs = 0.18033688011112042f;  // log2(e)/8
  bf16x8 qf[2][2];
#pragma unroll
  for (int mi = 0; mi < 2; mi++)
#pragma unroll
    for (int kh = 0; kh < 2; kh++) {
      const __bf16* src = QKV + (size_t)(q0 + w * 32 + mi * 16 + l15) * 3072 +
                          h * 64 + kh * 32 + quad * 8;
      bf16x8 r = *(const bf16x8*)src;
#pragma unroll
      for (int j = 0; j < 8; j++) r[j] = (__bf16)((float)r[j] * qs);
      qf[mi][kh] = r;
    }

  float mrow[2][4], lrow[2][4];
  f32x4 O[2][4] = {};
#pragma unroll
  for (int mi = 0; mi < 2; mi++)
#pragma unroll
    for (int r = 0; r < 4; r++) { mrow[mi][r] = -1e30f; lrow[mi][r] = 0.f; }

  for (int kt = 0; kt < 16; ++kt) {
    const int ktok = tok0 + kt * 128;
    // stage K tile [128 keys][64 d]
#pragma unroll
    for (int j = 0; j < 4; j++) {
      const int key = (t >> 3) + j * 32;
      const __bf16* gp =
          QKV + (size_t)(ktok + key) * 3072 + 1024 + h * 64 + (t & 7) * 8;
      async16(gp, Ks + t * 8 + j * 2048);
    }
    // stage V^T tile [64 d][128 keys]
#pragma unroll
    for (int j = 0; j < 4; j++) {
      const int d = (t >> 4) + j * 16;
      const __bf16* gp = VT + (size_t)(h * 64 + d) * 4096 + ktok + (t & 15) * 8;
      async16(gp, VTs + t * 8 + j * 2048);
    }
    __syncthreads();

    // S = Q K^T  (scaled into exp2 domain)
    f32x4 s[2][8] = {};
#pragma unroll
    for (int ni = 0; ni < 8; ni++) {
      bf16x8 k0 = *(const bf16x8*)&Ks[(ni * 16 + l15) * 64 + quad * 8];
      bf16x8 k1 = *(const bf16x8*)&Ks[(ni * 16 + l15) * 64 + 32 + quad * 8];
#pragma unroll
      for (int mi = 0; mi < 2; mi++) {
        s[mi][ni] = mfma16(qf[mi][0], k0, s[mi][ni]);
        s[mi][ni] = mfma16(qf[mi][1], k1, s[mi][ni]);
      }
    }

    // online softmax (rows = quad*4+r; cols across 16 lanes of the quad)
    float alpha[2][4];
#pragma unroll
    for (int mi = 0; mi < 2; mi++)
#pragma unroll
      for (int r = 0; r < 4; r++) {
        float mx = s[mi][0][r];
#pragma unroll
        for (int ni = 1; ni < 8; ni++) mx = fmaxf(mx, s[mi][ni][r]);
        mx = fmaxf(mx, __shfl_xor(mx, 1));
        mx = fmaxf(mx, __shfl_xor(mx, 2));
        mx = fmaxf(mx, __shfl_xor(mx, 4));
        mx = fmaxf(mx, __shfl_xor(mx, 8));
        const float mnew = fmaxf(mrow[mi][r], mx);
        const float al = __builtin_amdgcn_exp2f(mrow[mi][r] - mnew);
        float ps = 0.f;
#pragma unroll
        for (int ni = 0; ni < 8; ni++) {
          const float p = __builtin_amdgcn_exp2f(s[mi][ni][r] - mnew);
          s[mi][ni][r] = p;
          ps += p;
        }
        ps += __shfl_xor(ps, 1);
        ps += __shfl_xor(ps, 2);
        ps += __shfl_xor(ps, 4);
        ps += __shfl_xor(ps, 8);
        lrow[mi][r] = lrow[mi][r] * al + ps;
        mrow[mi][r] = mnew;
        alpha[mi][r] = al;
      }

    // write P (C-layout -> [q][key] LDS), rescale O
#pragma unroll
    for (int mi = 0; mi < 2; mi++)
#pragma unroll
      for (int ni = 0; ni < 8; ni++)
#pragma unroll
        for (int r = 0; r < 4; r++)
          Ps[w][(mi * 16 + quad * 4 + r) * 128 + ni * 16 + l15] =
              (__bf16)s[mi][ni][r];
#pragma unroll
    for (int mi = 0; mi < 2; mi++)
#pragma unroll
      for (int nd = 0; nd < 4; nd++)
#pragma unroll
        for (int r = 0; r < 4; r++) O[mi][nd][r] *= alpha[mi][r];
    __syncthreads();  // orders Ps writes before A-layout reads

    // O += P V  (A = P from LDS, B = V^T tile)
#pragma unroll
    for (int kc = 0; kc < 4; kc++) {
      bf16x8 pa0 = *(const bf16x8*)&Ps[w][(l15)*128 + kc * 32 + quad * 8];
      bf16x8 pa1 = *(const bf16x8*)&Ps[w][(16 + l15) * 128 + kc * 32 + quad * 8];
#pragma unroll
      for (int nd = 0; nd < 4; nd++) {
        bf16x8 vb =
            *(const bf16x8*)&VTs[(nd * 16 + l15) * 128 + kc * 32 + quad * 8];
        O[0][nd] = mfma16(pa0, vb, O[0][nd]);
        O[1][nd] = mfma16(pa1, vb, O[1][nd]);
      }
    }
    __syncthreads();  // protect Ks/VTs before next tile's staging
  }

  // epilogue: ctx[tok][h*64+d] = O / l
#pragma unroll
  for (int mi = 0; mi < 2; mi++) {
    float rl[4];
#pragma unroll
    for (int r = 0; r < 4; r++) rl[r] = 1.0f / lrow[mi][r];
#pragma unroll
    for (int nd = 0; nd < 4; nd++)
#pragma unroll
      for (int r = 0; r < 4; r++) {
        const int tokq = q0 + w * 32 + mi * 16 + quad * 4 + r;
        const int col = h * 64 + nd * 16 + l15;
        ctx[(size_t)tokq * 1024 + col] = (__bf16)(O[mi][nd][r] * rl[r]);
      }
  }
}

// ---------------------------------------------------------------------------
extern "C" void kernel_launch(void* const* d_in, const int* in_sizes, int n_in,
                              void* d_out, int out_size, void* d_ws,
                              size_t ws_size, hipStream_t stream) {
  (void)in_sizes; (void)n_in; (void)out_size; (void)ws_size;

  const float* x = (const float*)d_in[0];     // [2,2048,1024] f32
  const float* Wq = (const float*)d_in[1];    // [1024,1024]
  const float* Wk = (const float*)d_in[2];
  const float* Wv = (const float*)d_in[3];
  const float* Wo = (const float*)d_in[4];
  const float* b_o = (const float*)d_in[5];   // [1024]
  const float* W1 = (const float*)d_in[6];    // [1024,4096]
  const float* b1 = (const float*)d_in[7];    // [4096]
  const float* W2 = (const float*)d_in[8];    // [4096,1024]
  const float* b2 = (const float*)d_in[9];    // [1024]
  const float* ln1g = (const float*)d_in[10];
  const float* ln1b = (const float*)d_in[11];
  const float* ln2g = (const float*)d_in[12];
  const float* ln2b = (const float*)d_in[13];

  char* ws = (char*)d_ws;
  __bf16* WqkvT = (__bf16*)(ws + 0);          // [3072][1024]  6 MB
  __bf16* WoT = (__bf16*)(ws + 6291456);      // [1024][1024]  2 MB
  __bf16* W1T = (__bf16*)(ws + 8388608);      // [4096][1024]  8 MB
  __bf16* W2T = (__bf16*)(ws + 16777216);     // [1024][4096]  8 MB
  __bf16* h = (__bf16*)(ws + 25165824);       // [4096][1024]  8 MB (LN1 out; reused LN2 out)
  __bf16* QKV = (__bf16*)(ws + 33554432);     // [4096][3072] 24 MB
  __bf16* VT = (__bf16*)(ws + 58720256);      // [1024][4096]  8 MB
  __bf16* ctx = (__bf16*)(ws + 67108864);     // [4096][1024]  8 MB
  float* x1 = (float*)(ws + 75497472);        // [4096][1024] 16 MB f32 -> 88 MB total
  __bf16* f1 = QKV;                           // [4096][4096] 32 MB (spans QKV+VT, both dead)

  const dim3 blk(256);

  // weight transposes (f32 -> bf16, [N][K] layouts)
  transpose_f2b<<<dim3(16, 16), blk, 0, stream>>>(Wq, WqkvT, 1024, 1024);
  transpose_f2b<<<dim3(16, 16), blk, 0, stream>>>(Wk, WqkvT + 1048576, 1024, 1024);
  transpose_f2b<<<dim3(16, 16), blk, 0, stream>>>(Wv, WqkvT + 2097152, 1024, 1024);
  transpose_f2b<<<dim3(16, 16), blk, 0, stream>>>(Wo, WoT, 1024, 1024);
  transpose_f2b<<<dim3(64, 16), blk, 0, stream>>>(W1, W1T, 4096, 1024);
  transpose_f2b<<<dim3(16, 64), blk, 0, stream>>>(W2, W2T, 1024, 4096);

  // h = LN1(x)  (f32 in, bf16 out)
  ln_kernel<<<dim3(1024), blk, 0, stream>>>(x, ln1g, ln1b, h);

  // QKV = h @ [Wq|Wk|Wv]
  gemm_bt<0><<<dim3(24, 32), blk, 0, stream>>>(h, 1024, WqkvT, 1024, (void*)QKV,
                                               3072, 1024, nullptr, nullptr, 0);

  // VT = V^T  (V = QKV cols 2048..3071)
  transpose_bf16<<<dim3(16, 64), blk, 0, stream>>>(
      (const unsigned short*)(QKV + 2048), (unsigned short*)VT, 3072, 4096);

  // ctx = softmax(QK^T/8) V
  attn_kernel<<<dim3(16, 32), blk, 0, stream>>>(QKV, VT, ctx);

  // x1 = x + ctx @ Wo + b_o   (f32 residual stream)
  gemm_bt<1><<<dim3(8, 32), blk, 0, stream>>>(ctx, 1024, WoT, 1024, (void*)x1,
                                              1024, 1024, b_o, x, 1024);

  // h2 = LN2(x1)
  ln_kernel<<<dim3(1024), blk, 0, stream>>>(x1, ln2g, ln2b, h);

  // f1 = relu(h2 @ W1 + b1)
  gemm_bt<2><<<dim3(32, 32), blk, 0, stream>>>(h, 1024, W1T, 1024, (void*)f1,
                                               4096, 1024, b1, nullptr, 0);

  // out = x1 + f1 @ W2 + b2  (f32 out)
  gemm_bt<3><<<dim3(8, 32), blk, 0, stream>>>(f1, 4096, W2T, 4096, d_out, 1024,
                                              4096, b2, x1, 1024);
}

// Round 3
// 402.853 us; speedup vs baseline: 1.1820x; 1.1820x over previous
//
#include <hip/hip_runtime.h>
#include <cstdint>
#include <cstddef>

// ---------------------------------------------------------------------------
// EncoderBlock: pre-norm transformer block, f32 I/O, bf16 MFMA internals.
//   T(weights f32->bf16) -> LN1 -> GEMM(QKV fused) -> T(V) -> flash-attn(S^T)
//   -> GEMM(Wo,+b,+x)->x1(f32) -> LN2 -> GEMM(W1,+b,relu) -> GEMM(W2,+b,+x1)
// GEMMs: m97 structure, TM x 128 tile, BK=32, global_load_lds(16B).
// Attention: S^T trick (K*Q^T) keeps P in registers as the PV A-fragment
// (zero-padded K=16-in-K=32 mfma); Ks/VTs XOR-swizzled via global-side
// gather so all LDS reads are bank-uniform.
// ---------------------------------------------------------------------------

typedef __attribute__((ext_vector_type(8))) __bf16 bf16x8;
typedef __attribute__((ext_vector_type(4))) __bf16 bf16x4;
typedef __attribute__((ext_vector_type(4))) float f32x4;

__device__ __forceinline__ void async16(const void* g, void* l) {
  __builtin_amdgcn_global_load_lds(
      (__attribute__((address_space(1))) void*)g,
      (__attribute__((address_space(3))) void*)l, 16, 0, 0);
}

__device__ __forceinline__ f32x4 mfma16(bf16x8 a, bf16x8 b, f32x4 c) {
  return __builtin_amdgcn_mfma_f32_16x16x32_bf16(a, b, c, 0, 0, 0);
}

// ---------------------------------------------------------------------------
// f32 -> bf16 converting transpose: out[C][R] = (bf16)in[R][C].
// ---------------------------------------------------------------------------
__global__ __launch_bounds__(256) void transpose_f2b(
    const float* __restrict__ in, __bf16* __restrict__ out, int ld_in,
    int ld_out) {
  __shared__ __bf16 tile[64][65];
  const int c0 = blockIdx.x * 64, r0 = blockIdx.y * 64;
  const int tx = threadIdx.x & 63, ty = threadIdx.x >> 6;
#pragma unroll
  for (int i = 0; i < 16; i++) {
    int r = ty + i * 4;
    tile[r][tx] = (__bf16)in[(size_t)(r0 + r) * ld_in + c0 + tx];
  }
  __syncthreads();
#pragma unroll
  for (int i = 0; i < 16; i++) {
    int r = ty + i * 4;
    out[(size_t)(c0 + r) * ld_out + r0 + tx] = tile[tx][r];
  }
}

// bf16 transpose (V^T from QKV)
__global__ __launch_bounds__(256) void transpose_bf16(
    const unsigned short* __restrict__ in, unsigned short* __restrict__ out,
    int ld_in, int ld_out) {
  __shared__ unsigned short tile[64][65];
  const int c0 = blockIdx.x * 64, r0 = blockIdx.y * 64;
  const int tx = threadIdx.x & 63, ty = threadIdx.x >> 6;
#pragma unroll
  for (int i = 0; i < 16; i++) {
    int r = ty + i * 4;
    tile[r][tx] = in[(size_t)(r0 + r) * ld_in + c0 + tx];
  }
  __syncthreads();
#pragma unroll
  for (int i = 0; i < 16; i++) {
    int r = ty + i * 4;
    out[(size_t)(c0 + r) * ld_out + r0 + tx] = tile[tx][r];
  }
}

// ---------------------------------------------------------------------------
// LayerNorm over 1024 dims. f32 in, f32 gamma/beta, bf16 out. 1 wave/token.
// ---------------------------------------------------------------------------
__global__ __launch_bounds__(256) void ln_kernel(
    const float* __restrict__ xin, const float* __restrict__ g,
    const float* __restrict__ bt, __bf16* __restrict__ out) {
  const int tok = blockIdx.x * 4 + (threadIdx.x >> 6);
  const int lane = threadIdx.x & 63;
  const int base0 = lane * 8, base1 = 512 + lane * 8;
  const float* xr = xin + (size_t)tok * 1024;
  float v[16];
  float4 a0 = *(const float4*)(xr + base0);
  float4 a1 = *(const float4*)(xr + base0 + 4);
  float4 a2 = *(const float4*)(xr + base1);
  float4 a3 = *(const float4*)(xr + base1 + 4);
  v[0] = a0.x; v[1] = a0.y; v[2] = a0.z; v[3] = a0.w;
  v[4] = a1.x; v[5] = a1.y; v[6] = a1.z; v[7] = a1.w;
  v[8] = a2.x; v[9] = a2.y; v[10] = a2.z; v[11] = a2.w;
  v[12] = a3.x; v[13] = a3.y; v[14] = a3.z; v[15] = a3.w;
  float s = 0.f, s2 = 0.f;
#pragma unroll
  for (int i = 0; i < 16; i++) { s += v[i]; s2 += v[i] * v[i]; }
#pragma unroll
  for (int m = 1; m < 64; m <<= 1) {
    s += __shfl_xor(s, m);
    s2 += __shfl_xor(s2, m);
  }
  const float mean = s * (1.f / 1024.f);
  const float var = s2 * (1.f / 1024.f) - mean * mean;
  const float rstd = rsqrtf(var + 1e-6f);
  float4 g0 = *(const float4*)(g + base0), g1 = *(const float4*)(g + base0 + 4);
  float4 g2 = *(const float4*)(g + base1), g3 = *(const float4*)(g + base1 + 4);
  float4 b0 = *(const float4*)(bt + base0), b1v = *(const float4*)(bt + base0 + 4);
  float4 b2v = *(const float4*)(bt + base1), b3 = *(const float4*)(bt + base1 + 4);
  float gg[16] = {g0.x, g0.y, g0.z, g0.w, g1.x, g1.y, g1.z, g1.w,
                  g2.x, g2.y, g2.z, g2.w, g3.x, g3.y, g3.z, g3.w};
  float bb[16] = {b0.x, b0.y, b0.z, b0.w, b1v.x, b1v.y, b1v.z, b1v.w,
                  b2v.x, b2v.y, b2v.z, b2v.w, b3.x, b3.y, b3.z, b3.w};
  bf16x8 o0, o1;
#pragma unroll
  for (int j = 0; j < 8; j++) {
    o0[j] = (__bf16)((v[j] - mean) * rstd * gg[j] + bb[j]);
    o1[j] = (__bf16)((v[8 + j] - mean) * rstd * gg[8 + j] + bb[8 + j]);
  }
  __bf16* op = out + (size_t)tok * 1024;
  *(bf16x8*)(op + base0) = o0;
  *(bf16x8*)(op + base1) = o1;
}

// ---------------------------------------------------------------------------
// GEMM C[M,N] = A[M,K](bf16) * BT[N,K](bf16)^T (+epilogue). TM x 128 tile,
// BK=32, 256 thr = 2x2 waves. TM=128: wave 64x64 (acc 4x4). TM=64: wave
// 32x64 (acc 2x4) -> 2x more blocks for small grids (Wo/W2 were 1 block/CU).
// EPI: 0 ->bf16; 1/3 +bias(f32)+res(f32)->f32; 2 +bias,relu->bf16.
// ---------------------------------------------------------------------------
template <int EPI, int TM>
__global__ __launch_bounds__(256) void gemm_bt(
    const __bf16* __restrict__ A, int lda, const __bf16* __restrict__ BT,
    int ldb, void* __restrict__ C, int ldc, int K,
    const float* __restrict__ bias, const float* __restrict__ res, int ldres) {
  const int t = threadIdx.x;
  const int m0 = blockIdx.y * TM, n0 = blockIdx.x * 128;
  __shared__ __align__(16) __bf16 As[TM * 32];   // [m][k]
  __shared__ __align__(16) __bf16 Bs[128 * 32];  // [n][k]
  const int lane = t & 63, w = t >> 6;
  const int quad = lane >> 4, l15 = lane & 15;
  const int wm = w >> 1, wn = w & 1;
  constexpr int MF = TM / 32;  // m-fragments per wave

  f32x4 acc[MF][4] = {};

  const __bf16* ga = A + (size_t)(m0 + (t >> 2)) * lda + (t & 3) * 8;
  const __bf16* gb = BT + (size_t)(n0 + (t >> 2)) * ldb + (t & 3) * 8;
  __bf16* la = As + t * 8;
  __bf16* lb = Bs + t * 8;
  const size_t a64 = (size_t)64 * lda, b64 = (size_t)64 * ldb;

  for (int kk = 0; kk < K; kk += 32) {
#pragma unroll
    for (int i = 0; i < TM / 64; i++) async16(ga + i * a64, la + i * 2048);
    async16(gb, lb);
    async16(gb + b64, lb + 2048);
    ga += 32;
    gb += 32;
    __syncthreads();  // vmcnt(0) drain before barrier -> LDS data visible
    bf16x8 af[MF], bfr[4];
#pragma unroll
    for (int i = 0; i < MF; i++)
      af[i] = *(const bf16x8*)&As[(wm * (TM / 2) + i * 16 + l15) * 32 + quad * 8];
#pragma unroll
    for (int i = 0; i < 4; i++)
      bfr[i] = *(const bf16x8*)&Bs[(wn * 64 + i * 16 + l15) * 32 + quad * 8];
#pragma unroll
    for (int mi = 0; mi < MF; mi++)
#pragma unroll
      for (int ni = 0; ni < 4; ni++)
        acc[mi][ni] = mfma16(af[mi], bfr[ni], acc[mi][ni]);
    __syncthreads();
  }

  float biasv[4];
  if constexpr (EPI != 0) {
#pragma unroll
    for (int ni = 0; ni < 4; ni++)
      biasv[ni] = bias[n0 + wn * 64 + ni * 16 + l15];
  }
#pragma unroll
  for (int mi = 0; mi < MF; mi++)
#pragma unroll
    for (int ni = 0; ni < 4; ni++)
#pragma unroll
      for (int r = 0; r < 4; r++) {
        const int row = m0 + wm * (TM / 2) + mi * 16 + quad * 4 + r;
        const int col = n0 + wn * 64 + ni * 16 + l15;
        float v = acc[mi][ni][r];
        if constexpr (EPI == 0) {
          ((__bf16*)C)[(size_t)row * ldc + col] = (__bf16)v;
        } else if constexpr (EPI == 1 || EPI == 3) {
          v += biasv[ni] + res[(size_t)row * ldres + col];
          ((float*)C)[(size_t)row * ldc + col] = v;
        } else {  // EPI == 2
          v += biasv[ni];
          ((__bf16*)C)[(size_t)row * ldc + col] = (__bf16)fmaxf(v, 0.f);
        }
      }
}

// ---------------------------------------------------------------------------
// Flash attention via S^T. Block = 64 q x (one b,h); 256 thr, wave owns 16 q.
// S^T = K*Q^T so lane's C-layout regs S^T[key=quad*4+r][q=l15] ARE the PV
// A-fragment (keys at quad*4+j, zero-padded into the K=32 mfma; V-fragment
// padded identically -> exact). Softmax stats per-lane (q=l15), broadcast to
// O rows (q=quad*4+r) with 4 shfl. Ks swizzled at 16B, VTs at 8B (even
// swizzle preserves the 16B DMA chunk pairing) via global-side gather.
// ---------------------------------------------------------------------------
__global__ __launch_bounds__(256, 4) void attn_kernel(
    const __bf16* __restrict__ QKV, const __bf16* __restrict__ VT,
    __bf16* __restrict__ ctx) {
  const int qt = blockIdx.x, bh = blockIdx.y;
  const int b = bh >> 4, h = bh & 15;
  const int t = threadIdx.x, w = t >> 6, lane = t & 63;
  const int quad = lane >> 4, l15 = lane & 15;
  const int tok0 = b * 2048;
  const int q0w = tok0 + qt * 64 + w * 16;

  __shared__ __align__(16) __bf16 Ks[128 * 64];   // [key][d], 16B-swizzled
  __shared__ __align__(16) __bf16 VTs[64 * 128];  // [d][key], 8B-swizzled

  const float qs = 0.18033688011112042f;  // log2(e)/8 -> softmax in exp2 domain
  // Q rows as S^T B-operand: lane holds Q[q=l15][d=kb*32+quad*8+j]
  bf16x8 qf[2];
#pragma unroll
  for (int kb = 0; kb < 2; kb++) {
    const __bf16* src =
        QKV + (size_t)(q0w + l15) * 3072 + h * 64 + kb * 32 + quad * 8;
    bf16x8 r = *(const bf16x8*)src;
#pragma unroll
    for (int j = 0; j < 8; j++) r[j] = (__bf16)((float)r[j] * qs);
    qf[kb] = r;
  }

  float mrow = -1e30f, lrow = 0.f;
  f32x4 O[4] = {};

  // staging address components (global-side gather implements the swizzle)
  const int krow = t >> 3;                              // Ks row 0..31 (+j*32)
  const int kcg = (((t & 7) ^ (krow & 7)) * 8);         // Ks global elem off
  const int vrow = t >> 4;                              // VTs row 0..15 (+j*16)
  const int vcg = (((2 * (t & 15)) ^ ((vrow & 7) * 2)) * 4);  // even swizzle

  for (int kt = 0; kt < 16; ++kt) {
    const int ktok = tok0 + kt * 128;
#pragma unroll
    for (int j = 0; j < 4; j++) {
      const __bf16* gp =
          QKV + (size_t)(ktok + krow + j * 32) * 3072 + 1024 + h * 64 + kcg;
      async16(gp, Ks + t * 8 + j * 2048);
    }
#pragma unroll
    for (int j = 0; j < 4; j++) {
      const __bf16* gp =
          VT + (size_t)(h * 64 + vrow + j * 16) * 4096 + ktok + vcg;
      async16(gp, VTs + t * 8 + j * 2048);
    }
    __syncthreads();

    // S^T tiles: sT[kt8] = S^T[key=kt8*16+quad*4+r][q=l15]
    f32x4 sT[8];
#pragma unroll
    for (int kt8 = 0; kt8 < 8; kt8++) {
      f32x4 a = {};
#pragma unroll
      for (int kb = 0; kb < 2; kb++) {
        bf16x8 kf = *(const bf16x8*)&Ks[(kt8 * 16 + l15) * 64 +
                                        (((kb * 4 + quad) ^ (l15 & 7)) * 8)];
        a = mfma16(kf, qf[kb], a);
      }
      sT[kt8] = a;
    }

    // online softmax, stats per q=l15 (reduce in-lane then across quads)
    float mx = -1e30f;
#pragma unroll
    for (int kt8 = 0; kt8 < 8; kt8++)
#pragma unroll
      for (int r = 0; r < 4; r++) mx = fmaxf(mx, sT[kt8][r]);
    mx = fmaxf(mx, __shfl_xor(mx, 16));
    mx = fmaxf(mx, __shfl_xor(mx, 32));
    const float mnew = fmaxf(mrow, mx);
    const float alpha = __builtin_amdgcn_exp2f(mrow - mnew);
    float ps = 0.f;
#pragma unroll
    for (int kt8 = 0; kt8 < 8; kt8++)
#pragma unroll
      for (int r = 0; r < 4; r++) {
        const float p = __builtin_amdgcn_exp2f(sT[kt8][r] - mnew);
        sT[kt8][r] = p;
        ps += p;
      }
    ps += __shfl_xor(ps, 16);
    ps += __shfl_xor(ps, 32);
    lrow = lrow * alpha + ps;
    mrow = mnew;

    // rescale O: O rows are q=quad*4+r -> broadcast alpha from lane quad*4+r
    float aR[4];
#pragma unroll
    for (int r = 0; r < 4; r++) aR[r] = __shfl(alpha, quad * 4 + r);
#pragma unroll
    for (int nd = 0; nd < 4; nd++)
#pragma unroll
      for (int r = 0; r < 4; r++) O[nd][r] *= aR[r];

    // PV: A = P (in regs, keys quad*4+j, j<4; zero-pad j>=4),
    //     B = VT rows (same key placement, zero-padded) -> exact product
#pragma unroll
    for (int kb8 = 0; kb8 < 8; kb8++) {
      bf16x8 pf = {};
#pragma unroll
      for (int j = 0; j < 4; j++) pf[j] = (__bf16)sT[kb8][j];
#pragma unroll
      for (int nd = 0; nd < 4; nd++) {
        bf16x4 v4 = *(const bf16x4*)&VTs[(nd * 16 + l15) * 128 +
                                         (((kb8 * 4 + quad) ^ ((l15 & 7) * 2)) * 4)];
        bf16x8 vf = {};
#pragma unroll
        for (int j = 0; j < 4; j++) vf[j] = v4[j];
        O[nd] = mfma16(pf, vf, O[nd]);
      }
    }
    __syncthreads();  // protect Ks/VTs before next tile's staging
  }

  // epilogue: ctx[q][h*64+d] = O / l  (l broadcast like alpha)
  float rl[4];
#pragma unroll
  for (int r = 0; r < 4; r++) rl[r] = 1.0f / __shfl(lrow, quad * 4 + r);
#pragma unroll
  for (int nd = 0; nd < 4; nd++)
#pragma unroll
    for (int r = 0; r < 4; r++) {
      const int tokq = q0w + quad * 4 + r;
      const int col = h * 64 + nd * 16 + l15;
      ctx[(size_t)tokq * 1024 + col] = (__bf16)(O[nd][r] * rl[r]);
    }
}

// ---------------------------------------------------------------------------
extern "C" void kernel_launch(void* const* d_in, const int* in_sizes, int n_in,
                              void* d_out, int out_size, void* d_ws,
                              size_t ws_size, hipStream_t stream) {
  (void)in_sizes; (void)n_in; (void)out_size; (void)ws_size;

  const float* x = (const float*)d_in[0];
  const float* Wq = (const float*)d_in[1];
  const float* Wk = (const float*)d_in[2];
  const float* Wv = (const float*)d_in[3];
  const float* Wo = (const float*)d_in[4];
  const float* b_o = (const float*)d_in[5];
  const float* W1 = (const float*)d_in[6];
  const float* b1 = (const float*)d_in[7];
  const float* W2 = (const float*)d_in[8];
  const float* b2 = (const float*)d_in[9];
  const float* ln1g = (const float*)d_in[10];
  const float* ln1b = (const float*)d_in[11];
  const float* ln2g = (const float*)d_in[12];
  const float* ln2b = (const float*)d_in[13];

  char* ws = (char*)d_ws;
  __bf16* WqkvT = (__bf16*)(ws + 0);        // [3072][1024]  6 MB
  __bf16* WoT = (__bf16*)(ws + 6291456);    // [1024][1024]  2 MB
  __bf16* W1T = (__bf16*)(ws + 8388608);    // [4096][1024]  8 MB
  __bf16* W2T = (__bf16*)(ws + 16777216);   // [1024][4096]  8 MB
  __bf16* h = (__bf16*)(ws + 25165824);     // [4096][1024]  8 MB (LN1/LN2 out)
  __bf16* QKV = (__bf16*)(ws + 33554432);   // [4096][3072] 24 MB
  __bf16* VT = (__bf16*)(ws + 58720256);    // [1024][4096]  8 MB
  __bf16* ctx = (__bf16*)(ws + 67108864);   // [4096][1024]  8 MB
  float* x1 = (float*)(ws + 75497472);      // [4096][1024] 16 MB f32
  __bf16* f1 = QKV;                         // [4096][4096] 32 MB (QKV+VT dead)

  const dim3 blk(256);

  transpose_f2b<<<dim3(16, 16), blk, 0, stream>>>(Wq, WqkvT, 1024, 1024);
  transpose_f2b<<<dim3(16, 16), blk, 0, stream>>>(Wk, WqkvT + 1048576, 1024, 1024);
  transpose_f2b<<<dim3(16, 16), blk, 0, stream>>>(Wv, WqkvT + 2097152, 1024, 1024);
  transpose_f2b<<<dim3(16, 16), blk, 0, stream>>>(Wo, WoT, 1024, 1024);
  transpose_f2b<<<dim3(64, 16), blk, 0, stream>>>(W1, W1T, 4096, 1024);
  transpose_f2b<<<dim3(16, 64), blk, 0, stream>>>(W2, W2T, 1024, 4096);

  ln_kernel<<<dim3(1024), blk, 0, stream>>>(x, ln1g, ln1b, h);

  gemm_bt<0, 128><<<dim3(24, 32), blk, 0, stream>>>(
      h, 1024, WqkvT, 1024, (void*)QKV, 3072, 1024, nullptr, nullptr, 0);

  transpose_bf16<<<dim3(16, 64), blk, 0, stream>>>(
      (const unsigned short*)(QKV + 2048), (unsigned short*)VT, 3072, 4096);

  attn_kernel<<<dim3(32, 32), blk, 0, stream>>>(QKV, VT, ctx);

  gemm_bt<1, 64><<<dim3(8, 64), blk, 0, stream>>>(
      ctx, 1024, WoT, 1024, (void*)x1, 1024, 1024, b_o, x, 1024);

  ln_kernel<<<dim3(1024), blk, 0, stream>>>(x1, ln2g, ln2b, h);

  gemm_bt<2, 128><<<dim3(32, 32), blk, 0, stream>>>(
      h, 1024, W1T, 1024, (void*)f1, 4096, 1024, b1, nullptr, 0);

  gemm_bt<3, 64><<<dim3(8, 64), blk, 0, stream>>>(
      f1, 4096, W2T, 4096, d_out, 1024, 4096, b2, x1, 1024);
}

// Round 4
// 395.595 us; speedup vs baseline: 1.2037x; 1.0183x over previous
//
#include <hip/hip_runtime.h>
#include <cstdint>
#include <cstddef>

// ---------------------------------------------------------------------------
// EncoderBlock: pre-norm transformer block, f32 I/O, bf16 MFMA internals.
//   T(weights f32->bf16) -> LN1 -> GEMM(QKV fused) -> T(V) -> flash-attn(S^T)
//   -> GEMM(Wo, split-K=2) + reduce(+b_o,+x)->x1(f32) -> LN2
//   -> GEMM(W1,+b,relu) -> GEMM(W2, split-K=2) + reduce(+b2,+x1)->d_out
// GEMMs: TM x 128 tile, BK=32, global_load_lds(16B), DOUBLE-BUFFERED K-loop
// (prefetch next tile during MFMA; 1 barrier/iter). Split-K partials in bf16.
// Attention: S^T trick (K*Q^T) keeps P in registers as the PV A-fragment;
// Ks/VTs XOR-swizzled via global-side gather (bank-uniform LDS reads).
// ---------------------------------------------------------------------------

typedef __attribute__((ext_vector_type(8))) __bf16 bf16x8;
typedef __attribute__((ext_vector_type(4))) __bf16 bf16x4;
typedef __attribute__((ext_vector_type(4))) float f32x4;

__device__ __forceinline__ void async16(const void* g, void* l) {
  __builtin_amdgcn_global_load_lds(
      (__attribute__((address_space(1))) void*)g,
      (__attribute__((address_space(3))) void*)l, 16, 0, 0);
}

__device__ __forceinline__ f32x4 mfma16(bf16x8 a, bf16x8 b, f32x4 c) {
  return __builtin_amdgcn_mfma_f32_16x16x32_bf16(a, b, c, 0, 0, 0);
}

// ---------------------------------------------------------------------------
// f32 -> bf16 converting transpose: out[C][R] = (bf16)in[R][C].
// ---------------------------------------------------------------------------
__global__ __launch_bounds__(256) void transpose_f2b(
    const float* __restrict__ in, __bf16* __restrict__ out, int ld_in,
    int ld_out) {
  __shared__ __bf16 tile[64][65];
  const int c0 = blockIdx.x * 64, r0 = blockIdx.y * 64;
  const int tx = threadIdx.x & 63, ty = threadIdx.x >> 6;
#pragma unroll
  for (int i = 0; i < 16; i++) {
    int r = ty + i * 4;
    tile[r][tx] = (__bf16)in[(size_t)(r0 + r) * ld_in + c0 + tx];
  }
  __syncthreads();
#pragma unroll
  for (int i = 0; i < 16; i++) {
    int r = ty + i * 4;
    out[(size_t)(c0 + r) * ld_out + r0 + tx] = tile[tx][r];
  }
}

// bf16 transpose (V^T from QKV)
__global__ __launch_bounds__(256) void transpose_bf16(
    const unsigned short* __restrict__ in, unsigned short* __restrict__ out,
    int ld_in, int ld_out) {
  __shared__ unsigned short tile[64][65];
  const int c0 = blockIdx.x * 64, r0 = blockIdx.y * 64;
  const int tx = threadIdx.x & 63, ty = threadIdx.x >> 6;
#pragma unroll
  for (int i = 0; i < 16; i++) {
    int r = ty + i * 4;
    tile[r][tx] = in[(size_t)(r0 + r) * ld_in + c0 + tx];
  }
  __syncthreads();
#pragma unroll
  for (int i = 0; i < 16; i++) {
    int r = ty + i * 4;
    out[(size_t)(c0 + r) * ld_out + r0 + tx] = tile[tx][r];
  }
}

// ---------------------------------------------------------------------------
// LayerNorm over 1024 dims. f32 in, f32 gamma/beta, bf16 out. 1 wave/token.
// ---------------------------------------------------------------------------
__global__ __launch_bounds__(256) void ln_kernel(
    const float* __restrict__ xin, const float* __restrict__ g,
    const float* __restrict__ bt, __bf16* __restrict__ out) {
  const int tok = blockIdx.x * 4 + (threadIdx.x >> 6);
  const int lane = threadIdx.x & 63;
  const int base0 = lane * 8, base1 = 512 + lane * 8;
  const float* xr = xin + (size_t)tok * 1024;
  float v[16];
  float4 a0 = *(const float4*)(xr + base0);
  float4 a1 = *(const float4*)(xr + base0 + 4);
  float4 a2 = *(const float4*)(xr + base1);
  float4 a3 = *(const float4*)(xr + base1 + 4);
  v[0] = a0.x; v[1] = a0.y; v[2] = a0.z; v[3] = a0.w;
  v[4] = a1.x; v[5] = a1.y; v[6] = a1.z; v[7] = a1.w;
  v[8] = a2.x; v[9] = a2.y; v[10] = a2.z; v[11] = a2.w;
  v[12] = a3.x; v[13] = a3.y; v[14] = a3.z; v[15] = a3.w;
  float s = 0.f, s2 = 0.f;
#pragma unroll
  for (int i = 0; i < 16; i++) { s += v[i]; s2 += v[i] * v[i]; }
#pragma unroll
  for (int m = 1; m < 64; m <<= 1) {
    s += __shfl_xor(s, m);
    s2 += __shfl_xor(s2, m);
  }
  const float mean = s * (1.f / 1024.f);
  const float var = s2 * (1.f / 1024.f) - mean * mean;
  const float rstd = rsqrtf(var + 1e-6f);
  float4 g0 = *(const float4*)(g + base0), g1 = *(const float4*)(g + base0 + 4);
  float4 g2 = *(const float4*)(g + base1), g3 = *(const float4*)(g + base1 + 4);
  float4 b0 = *(const float4*)(bt + base0), b1v = *(const float4*)(bt + base0 + 4);
  float4 b2v = *(const float4*)(bt + base1), b3 = *(const float4*)(bt + base1 + 4);
  float gg[16] = {g0.x, g0.y, g0.z, g0.w, g1.x, g1.y, g1.z, g1.w,
                  g2.x, g2.y, g2.z, g2.w, g3.x, g3.y, g3.z, g3.w};
  float bb[16] = {b0.x, b0.y, b0.z, b0.w, b1v.x, b1v.y, b1v.z, b1v.w,
                  b2v.x, b2v.y, b2v.z, b2v.w, b3.x, b3.y, b3.z, b3.w};
  bf16x8 o0, o1;
#pragma unroll
  for (int j = 0; j < 8; j++) {
    o0[j] = (__bf16)((v[j] - mean) * rstd * gg[j] + bb[j]);
    o1[j] = (__bf16)((v[8 + j] - mean) * rstd * gg[8 + j] + bb[8 + j]);
  }
  __bf16* op = out + (size_t)tok * 1024;
  *(bf16x8*)(op + base0) = o0;
  *(bf16x8*)(op + base1) = o1;
}

// ---------------------------------------------------------------------------
// GEMM C[M,N] = A[M,K](bf16) * BT[N,K](bf16)^T (+epilogue). TM x 128 tile,
// BK=32, 256 thr = 2x2 waves, DOUBLE-BUFFERED LDS (prefetch next K-tile
// during MFMA, one barrier per iteration).
// SPLITS>1: blockIdx.z = K-slice (Kb = per-block K); slice s writes its own
// bf16 partial at C + s*M*ldc (reduced by reduce_split).
// EPI: 0 ->bf16 (plain / split partial); 1 +bias(f32)+res(f32)->f32;
//      2 +bias,relu->bf16.
// ---------------------------------------------------------------------------
template <int EPI, int TM, int SPLITS = 1>
__global__ __launch_bounds__(256) void gemm_bt(
    const __bf16* __restrict__ A, int lda, const __bf16* __restrict__ BT,
    int ldb, void* __restrict__ C, int ldc, int Kb,
    const float* __restrict__ bias, const float* __restrict__ res, int ldres) {
  const int t = threadIdx.x;
  const int m0 = blockIdx.y * TM, n0 = blockIdx.x * 128;
  const int kz = (SPLITS > 1) ? blockIdx.z : 0;
  __shared__ __align__(16) __bf16 As[2][TM * 32];   // [m][k]
  __shared__ __align__(16) __bf16 Bs[2][128 * 32];  // [n][k]
  const int lane = t & 63, w = t >> 6;
  const int quad = lane >> 4, l15 = lane & 15;
  const int wm = w >> 1, wn = w & 1;
  constexpr int MF = TM / 32;  // m-fragments per wave

  f32x4 acc[MF][4] = {};

  const __bf16* ga =
      A + (size_t)(m0 + (t >> 2)) * lda + (t & 3) * 8 + (size_t)kz * Kb;
  const __bf16* gb =
      BT + (size_t)(n0 + (t >> 2)) * ldb + (t & 3) * 8 + (size_t)kz * Kb;
  const size_t a64 = (size_t)64 * lda, b64 = (size_t)64 * ldb;

  auto stage = [&](int buf) {
#pragma unroll
    for (int i = 0; i < TM / 64; i++)
      async16(ga + i * a64, As[buf] + t * 8 + i * 2048);
    async16(gb, Bs[buf] + t * 8);
    async16(gb + b64, Bs[buf] + t * 8 + 2048);
  };
  auto compute = [&](int buf) {
    bf16x8 af[MF], bfr[4];
#pragma unroll
    for (int i = 0; i < MF; i++)
      af[i] =
          *(const bf16x8*)&As[buf][(wm * (TM / 2) + i * 16 + l15) * 32 + quad * 8];
#pragma unroll
    for (int i = 0; i < 4; i++)
      bfr[i] = *(const bf16x8*)&Bs[buf][(wn * 64 + i * 16 + l15) * 32 + quad * 8];
#pragma unroll
    for (int mi = 0; mi < MF; mi++)
#pragma unroll
      for (int ni = 0; ni < 4; ni++)
        acc[mi][ni] = mfma16(af[mi], bfr[ni], acc[mi][ni]);
  };

  stage(0);
  ga += 32;
  gb += 32;
  __syncthreads();  // drain prologue loads
  int cur = 0;
  const int iters = Kb / 32;
  for (int it = 0; it < iters - 1; ++it) {
    stage(cur ^ 1);  // prefetch next tile (in flight during compute)
    ga += 32;
    gb += 32;
    compute(cur);
    __syncthreads();  // drains prefetch + protects cur for re-staging
    cur ^= 1;
  }
  compute(cur);

  float biasv[4];
  if constexpr (EPI == 1 || EPI == 2) {
#pragma unroll
    for (int ni = 0; ni < 4; ni++)
      biasv[ni] = bias[n0 + wn * 64 + ni * 16 + l15];
  }
  __bf16* Cb = (__bf16*)C;
  if constexpr (SPLITS > 1)
    Cb += (size_t)kz * gridDim.y * TM * ldc;  // partial slice
#pragma unroll
  for (int mi = 0; mi < MF; mi++)
#pragma unroll
    for (int ni = 0; ni < 4; ni++)
#pragma unroll
      for (int r = 0; r < 4; r++) {
        const int row = m0 + wm * (TM / 2) + mi * 16 + quad * 4 + r;
        const int col = n0 + wn * 64 + ni * 16 + l15;
        float v = acc[mi][ni][r];
        if constexpr (EPI == 0) {
          Cb[(size_t)row * ldc + col] = (__bf16)v;
        } else if constexpr (EPI == 1) {
          v += biasv[ni] + res[(size_t)row * ldres + col];
          ((float*)C)[(size_t)row * ldc + col] = v;
        } else {  // EPI == 2
          v += biasv[ni];
          ((__bf16*)C)[(size_t)row * ldc + col] = (__bf16)fmaxf(v, 0.f);
        }
      }
}

// ---------------------------------------------------------------------------
// Split-K reduce: out[row][col] = P0 + P1 + bias[col] + res[row][col] (f32).
// P = two bf16 partials of 4096x1024, contiguous. Grid 4096, 256 thr x4 cols.
// ---------------------------------------------------------------------------
__global__ __launch_bounds__(256) void reduce_split(
    const __bf16* __restrict__ P, const float* __restrict__ bias,
    const float* __restrict__ res, float* __restrict__ out) {
  const int row = blockIdx.x, c = threadIdx.x * 4;
  const size_t i = (size_t)row * 1024 + c;
  bf16x4 p0 = *(const bf16x4*)(P + i);
  bf16x4 p1 = *(const bf16x4*)(P + 4194304 + i);
  float4 r = *(const float4*)(res + i);
  float4 bv = *(const float4*)(bias + c);
  float4 o;
  o.x = (float)p0[0] + (float)p1[0] + r.x + bv.x;
  o.y = (float)p0[1] + (float)p1[1] + r.y + bv.y;
  o.z = (float)p0[2] + (float)p1[2] + r.z + bv.z;
  o.w = (float)p0[3] + (float)p1[3] + r.w + bv.w;
  *(float4*)(out + i) = o;
}

// ---------------------------------------------------------------------------
// Flash attention via S^T. Block = 64 q x (one b,h); 256 thr, wave owns 16 q.
// S^T = K*Q^T so lane's C-layout regs S^T[key=quad*4+r][q=l15] ARE the PV
// A-fragment (keys at quad*4+j, zero-padded into the K=32 mfma; V-fragment
// padded identically -> exact). Softmax stats per-lane (q=l15). Ks swizzled
// at 16B, VTs at 8B via global-side gather (bank-uniform LDS reads).
// ---------------------------------------------------------------------------
__global__ __launch_bounds__(256, 4) void attn_kernel(
    const __bf16* __restrict__ QKV, const __bf16* __restrict__ VT,
    __bf16* __restrict__ ctx) {
  const int qt = blockIdx.x, bh = blockIdx.y;
  const int b = bh >> 4, h = bh & 15;
  const int t = threadIdx.x, w = t >> 6, lane = t & 63;
  const int quad = lane >> 4, l15 = lane & 15;
  const int tok0 = b * 2048;
  const int q0w = tok0 + qt * 64 + w * 16;

  __shared__ __align__(16) __bf16 Ks[128 * 64];   // [key][d], 16B-swizzled
  __shared__ __align__(16) __bf16 VTs[64 * 128];  // [d][key], 8B-swizzled

  const float qs = 0.18033688011112042f;  // log2(e)/8 -> exp2-domain softmax
  bf16x8 qf[2];
#pragma unroll
  for (int kb = 0; kb < 2; kb++) {
    const __bf16* src =
        QKV + (size_t)(q0w + l15) * 3072 + h * 64 + kb * 32 + quad * 8;
    bf16x8 r = *(const bf16x8*)src;
#pragma unroll
    for (int j = 0; j < 8; j++) r[j] = (__bf16)((float)r[j] * qs);
    qf[kb] = r;
  }

  float mrow = -1e30f, lrow = 0.f;
  f32x4 O[4] = {};

  const int krow = t >> 3;
  const int kcg = (((t & 7) ^ (krow & 7)) * 8);
  const int vrow = t >> 4;
  const int vcg = (((2 * (t & 15)) ^ ((vrow & 7) * 2)) * 4);

  for (int kt = 0; kt < 16; ++kt) {
    const int ktok = tok0 + kt * 128;
#pragma unroll
    for (int j = 0; j < 4; j++) {
      const __bf16* gp =
          QKV + (size_t)(ktok + krow + j * 32) * 3072 + 1024 + h * 64 + kcg;
      async16(gp, Ks + t * 8 + j * 2048);
    }
#pragma unroll
    for (int j = 0; j < 4; j++) {
      const __bf16* gp =
          VT + (size_t)(h * 64 + vrow + j * 16) * 4096 + ktok + vcg;
      async16(gp, VTs + t * 8 + j * 2048);
    }
    __syncthreads();

    f32x4 sT[8];
#pragma unroll
    for (int kt8 = 0; kt8 < 8; kt8++) {
      f32x4 a = {};
#pragma unroll
      for (int kb = 0; kb < 2; kb++) {
        bf16x8 kf = *(const bf16x8*)&Ks[(kt8 * 16 + l15) * 64 +
                                        (((kb * 4 + quad) ^ (l15 & 7)) * 8)];
        a = mfma16(kf, qf[kb], a);
      }
      sT[kt8] = a;
    }

    float mx = -1e30f;
#pragma unroll
    for (int kt8 = 0; kt8 < 8; kt8++)
#pragma unroll
      for (int r = 0; r < 4; r++) mx = fmaxf(mx, sT[kt8][r]);
    mx = fmaxf(mx, __shfl_xor(mx, 16));
    mx = fmaxf(mx, __shfl_xor(mx, 32));
    const float mnew = fmaxf(mrow, mx);
    const float alpha = __builtin_amdgcn_exp2f(mrow - mnew);
    float ps = 0.f;
#pragma unroll
    for (int kt8 = 0; kt8 < 8; kt8++)
#pragma unroll
      for (int r = 0; r < 4; r++) {
        const float p = __builtin_amdgcn_exp2f(sT[kt8][r] - mnew);
        sT[kt8][r] = p;
        ps += p;
      }
    ps += __shfl_xor(ps, 16);
    ps += __shfl_xor(ps, 32);
    lrow = lrow * alpha + ps;
    mrow = mnew;

    float aR[4];
#pragma unroll
    for (int r = 0; r < 4; r++) aR[r] = __shfl(alpha, quad * 4 + r);
#pragma unroll
    for (int nd = 0; nd < 4; nd++)
#pragma unroll
      for (int r = 0; r < 4; r++) O[nd][r] *= aR[r];

#pragma unroll
    for (int kb8 = 0; kb8 < 8; kb8++) {
      bf16x8 pf = {};
#pragma unroll
      for (int j = 0; j < 4; j++) pf[j] = (__bf16)sT[kb8][j];
#pragma unroll
      for (int nd = 0; nd < 4; nd++) {
        bf16x4 v4 = *(const bf16x4*)&VTs[(nd * 16 + l15) * 128 +
                                         (((kb8 * 4 + quad) ^ ((l15 & 7) * 2)) * 4)];
        bf16x8 vf = {};
#pragma unroll
        for (int j = 0; j < 4; j++) vf[j] = v4[j];
        O[nd] = mfma16(pf, vf, O[nd]);
      }
    }
    __syncthreads();
  }

  float rl[4];
#pragma unroll
  for (int r = 0; r < 4; r++) rl[r] = 1.0f / __shfl(lrow, quad * 4 + r);
#pragma unroll
  for (int nd = 0; nd < 4; nd++)
#pragma unroll
    for (int r = 0; r < 4; r++) {
      const int tokq = q0w + quad * 4 + r;
      const int col = h * 64 + nd * 16 + l15;
      ctx[(size_t)tokq * 1024 + col] = (__bf16)(O[nd][r] * rl[r]);
    }
}

// ---------------------------------------------------------------------------
extern "C" void kernel_launch(void* const* d_in, const int* in_sizes, int n_in,
                              void* d_out, int out_size, void* d_ws,
                              size_t ws_size, hipStream_t stream) {
  (void)in_sizes; (void)n_in; (void)out_size; (void)ws_size;

  const float* x = (const float*)d_in[0];
  const float* Wq = (const float*)d_in[1];
  const float* Wk = (const float*)d_in[2];
  const float* Wv = (const float*)d_in[3];
  const float* Wo = (const float*)d_in[4];
  const float* b_o = (const float*)d_in[5];
  const float* W1 = (const float*)d_in[6];
  const float* b1 = (const float*)d_in[7];
  const float* W2 = (const float*)d_in[8];
  const float* b2 = (const float*)d_in[9];
  const float* ln1g = (const float*)d_in[10];
  const float* ln1b = (const float*)d_in[11];
  const float* ln2g = (const float*)d_in[12];
  const float* ln2b = (const float*)d_in[13];

  char* ws = (char*)d_ws;
  __bf16* WqkvT = (__bf16*)(ws + 0);        // [3072][1024]  6 MB
  __bf16* WoT = (__bf16*)(ws + 6291456);    // [1024][1024]  2 MB
  __bf16* W1T = (__bf16*)(ws + 8388608);    // [4096][1024]  8 MB
  __bf16* W2T = (__bf16*)(ws + 16777216);   // [1024][4096]  8 MB
  __bf16* h = (__bf16*)(ws + 25165824);     // [4096][1024]  8 MB (LN1/LN2 out)
  __bf16* QKV = (__bf16*)(ws + 33554432);   // [4096][3072] 24 MB
  __bf16* VT = (__bf16*)(ws + 58720256);    // [1024][4096]  8 MB
  __bf16* ctx = (__bf16*)(ws + 67108864);   // [4096][1024]  8 MB
  float* x1 = (float*)(ws + 75497472);      // [4096][1024] 16 MB f32
  __bf16* f1 = QKV;                         // [4096][4096] 32 MB (QKV+VT dead)
  // split-K partials (2 x 8 MB bf16, temporally dead regions):
  __bf16* Pwo = QKV;                        // Wo partials: QKV dead post-attn
  __bf16* Pw2 = (__bf16*)(ws + 0);          // W2 partials: WqkvT/WoT/W1T dead

  const dim3 blk(256);

  transpose_f2b<<<dim3(16, 16), blk, 0, stream>>>(Wq, WqkvT, 1024, 1024);
  transpose_f2b<<<dim3(16, 16), blk, 0, stream>>>(Wk, WqkvT + 1048576, 1024, 1024);
  transpose_f2b<<<dim3(16, 16), blk, 0, stream>>>(Wv, WqkvT + 2097152, 1024, 1024);
  transpose_f2b<<<dim3(16, 16), blk, 0, stream>>>(Wo, WoT, 1024, 1024);
  transpose_f2b<<<dim3(64, 16), blk, 0, stream>>>(W1, W1T, 4096, 1024);
  transpose_f2b<<<dim3(16, 64), blk, 0, stream>>>(W2, W2T, 1024, 4096);

  ln_kernel<<<dim3(1024), blk, 0, stream>>>(x, ln1g, ln1b, h);

  gemm_bt<0, 128><<<dim3(24, 32), blk, 0, stream>>>(
      h, 1024, WqkvT, 1024, (void*)QKV, 3072, 1024, nullptr, nullptr, 0);

  transpose_bf16<<<dim3(16, 64), blk, 0, stream>>>(
      (const unsigned short*)(QKV + 2048), (unsigned short*)VT, 3072, 4096);

  attn_kernel<<<dim3(32, 32), blk, 0, stream>>>(QKV, VT, ctx);

  // x1 = x + ctx@Wo + b_o : split-K=2 (Kb=512) -> bf16 partials -> reduce
  gemm_bt<0, 64, 2><<<dim3(8, 64, 2), blk, 0, stream>>>(
      ctx, 1024, WoT, 1024, (void*)Pwo, 1024, 512, nullptr, nullptr, 0);
  reduce_split<<<dim3(4096), blk, 0, stream>>>(Pwo, b_o, x, x1);

  ln_kernel<<<dim3(1024), blk, 0, stream>>>(x1, ln2g, ln2b, h);

  gemm_bt<2, 128><<<dim3(32, 32), blk, 0, stream>>>(
      h, 1024, W1T, 1024, (void*)f1, 4096, 1024, b1, nullptr, 0);

  // out = x1 + f1@W2 + b2 : split-K=2 (Kb=2048), TM=128 -> partials -> reduce
  gemm_bt<0, 128, 2><<<dim3(8, 32, 2), blk, 0, stream>>>(
      f1, 4096, W2T, 4096, (void*)Pw2, 1024, 2048, nullptr, nullptr, 0);
  reduce_split<<<dim3(4096), blk, 0, stream>>>(Pw2, b2, x1, (float*)d_out);
}